// Round 11
// baseline (779.666 us; speedup 1.0000x reference)
//
#include <hip/hip_runtime.h>
#include <hip/hip_bf16.h>

#define NB 16384
#define NT 32
#define NI 27
#define NH 32
#define NG 26

typedef __attribute__((ext_vector_type(8))) short bf16x8;
typedef __attribute__((ext_vector_type(4))) float f32x4;
typedef __attribute__((ext_vector_type(4))) int   i32x4;

#define MFMA(a, b, c) __builtin_amdgcn_mfma_f32_16x16x32_bf16((a), (b), (c), 0, 0, 0)
#define SWZ_XOR8 0x201F   // BitMode: xor=8, and=0x1F, or=0 -> lane <-> lane^8

static __device__ __forceinline__ int pack2(float lo, float hi) {
    unsigned short a = __builtin_bit_cast(unsigned short, __float2bfloat16(lo));
    unsigned short b = __builtin_bit_cast(unsigned short, __float2bfloat16(hi));
    return (int)(((unsigned)b << 16) | (unsigned)a);
}

// MFMA A-fragment loader. perm=false: lane supplies cols kbase+8*g4+2q(+1).
// perm=true: columns permuted by pi(8*g4+j) = 16*(j>>2) + 4*g4 + (j&3) so the
// B-operand can be packed directly from act-layout registers (verified R9).
static __device__ __forceinline__ bf16x8 load_wfrag(const float* __restrict__ W,
                                                    int rowlen, int nrows, int row,
                                                    int g4, int kbase, bool perm) {
    int w[4];
#pragma unroll
    for (int q = 0; q < 4; ++q) {
        int klo = perm ? (16 * (q >> 1) + 4 * g4 + ((2 * q) & 3))
                       : (kbase + 8 * g4 + 2 * q);
        int khi = klo + 1;
        float lo = (row < nrows && klo < rowlen) ? W[row * rowlen + klo] : 0.0f;
        float hi = (row < nrows && khi < rowlen) ? W[row * rowlen + khi] : 0.0f;
        w[q] = pack2(lo, hi);
    }
    i32x4 v = { w[0], w[1], w[2], w[3] };
    return __builtin_bit_cast(bf16x8, v);
}

// Own-half act values (hn[r] = h[16*mh_own + 4*g4 + r]) -> full pi-order B-frag:
// exchange the 2 packed words with the partner lane (lane^8, other col-copy of
// the same batch) via conflict-free ds_swizzle, then order by mh_own.
// Verified correct in R10 (absmax matched R9).
static __device__ __forceinline__ bf16x8 join_bfrag(const float hn[4], bool mh1) {
    int p0 = pack2(hn[0], hn[1]);
    int p1 = pack2(hn[2], hn[3]);
    int q0 = __builtin_amdgcn_ds_swizzle(p0, SWZ_XOR8);
    int q1 = __builtin_amdgcn_ds_swizzle(p1, SWZ_XOR8);
    i32x4 v = { mh1 ? q0 : p0, mh1 ? q1 : p1, mh1 ? p0 : q0, mh1 ? p1 : q1 };
    return __builtin_bit_cast(bf16x8, v);
}

// 8 batches/wave, each batch duplicated into cols bl and bl+8. MFMA computes
// gates twice (cheap pipe); activation work is split by col-copy -> per-lane
// trans/VALU act work halves. 2048 waves; NO launch_bounds min-waves arg:
// R10's (256,2) capped VGPR at 128 -> 216 MB scratch spill (the 738 us).
// Natural allocation (~228, like R9) fits 2 waves/SIMD in the 512-reg pool.
__global__ __launch_bounds__(256)
void lstm_dup2(const float* __restrict__ X,   // [B,T,I] flat, consumed as [T,B,I]
               const float* __restrict__ Gu,  // [B,26]
               const float* __restrict__ H0, const float* __restrict__ C0,
               const float* __restrict__ Wih0, const float* __restrict__ Whh0,
               const float* __restrict__ bih0, const float* __restrict__ bhh0,
               const float* __restrict__ Wih1, const float* __restrict__ Whh1,
               const float* __restrict__ bih1, const float* __restrict__ bhh1,
               const float* __restrict__ Wfc, const float* __restrict__ bfc,
               float* __restrict__ out)
{
    const int lane = threadIdx.x & 63;
    const int bl   = lane & 15;          // col (batch slot; two cols per batch)
    const int g4   = lane >> 4;
    const int k0   = 8 * g4;
    const int wid  = blockIdx.x * (blockDim.x >> 6) + (threadIdx.x >> 6);
    const int batch = wid * 8 + (bl & 7);   // 8 real batches per wave
    const int mh   = bl >> 3;               // owned hidden half: 0 -> [0,16), 1 -> [16,32)
    const bool mh1 = mh != 0;

    // ---------- persistent weights (h-consumers pi-permuted) ----------
    bf16x8 A0x[8], A0h[8], A1i[8], A1h[8];
    f32x4  b0[8], b1[8];
#pragma unroll
    for (int m = 0; m < 8; ++m) {
        A0x[m] = load_wfrag(Wih0, NI, 4 * NH, 16 * m + bl, g4, 0, false);
        A0h[m] = load_wfrag(Whh0, NH, 4 * NH, 16 * m + bl, g4, 0, true);
        A1i[m] = load_wfrag(Wih1, NH, 4 * NH, 16 * m + bl, g4, 0, true);
        A1h[m] = load_wfrag(Whh1, NH, 4 * NH, 16 * m + bl, g4, 0, true);
#pragma unroll
        for (int r = 0; r < 4; ++r) {
            int gr = 16 * m + 4 * g4 + r;
            b0[m][r] = bih0[gr] + bhh0[gr];
            b1[m][r] = bih1[gr] + bhh1[gr];
        }
    }
    bf16x8 Afc0[2], Afc1[2];
#pragma unroll
    for (int m2 = 0; m2 < 2; ++m2) {
        Afc0[m2] = load_wfrag(Wfc, NH + NG, NG, 16 * m2 + bl, g4, 0, true);
        Afc1[m2] = load_wfrag(Wfc, NH + NG, NG, 16 * m2 + bl, g4, NH, false);
    }

    // ---------- state init (init aliases h0/c0; both col-copies identical) ----------
    const float* h0p = H0 + (size_t)batch * NH;
    const float* c0p = C0 + (size_t)batch * NH;
    i32x4 hv = { pack2(h0p[4 * g4],          h0p[4 * g4 + 1]),
                 pack2(h0p[4 * g4 + 2],      h0p[4 * g4 + 3]),
                 pack2(h0p[16 + 4 * g4],     h0p[16 + 4 * g4 + 1]),
                 pack2(h0p[16 + 4 * g4 + 2], h0p[16 + 4 * g4 + 3]) };
    bf16x8 h1f = __builtin_bit_cast(bf16x8, hv);
    bf16x8 h2f = h1f;
    float c1[4], c2[4], hsum[4];
#pragma unroll
    for (int r = 0; r < 4; ++r) {
        float c = c0p[16 * mh + 4 * g4 + r];   // own units only
        c1[r] = c; c2[r] = c; hsum[r] = 0.0f;
    }

    // x prefetch (t=0); both col-copies load the same addresses (cache-served)
    float xn[8];
    {
        const float* xp = X + (size_t)batch * NI;
#pragma unroll
        for (int j = 0; j < 8; ++j) { int k = k0 + j; xn[j] = (k < NI) ? xp[k] : 0.0f; }
    }

#pragma unroll 1
    for (int t = 0; t < NT; ++t) {
        int xw[4];
#pragma unroll
        for (int q = 0; q < 4; ++q) xw[q] = pack2(xn[2 * q], xn[2 * q + 1]);
        i32x4 xv = { xw[0], xw[1], xw[2], xw[3] };
        bf16x8 xf = __builtin_bit_cast(bf16x8, xv);
        if (t + 1 < NT) {
            const float* xp = X + ((size_t)(t + 1) * NB + batch) * NI;
#pragma unroll
            for (int j = 0; j < 8; ++j) { int k = k0 + j; xn[j] = (k < NI) ? xp[k] : 0.0f; }
        }

        f32x4 g[8];
        // ---------- layer 0 ----------
#pragma unroll
        for (int m = 0; m < 8; ++m) g[m] = MFMA(A0x[m], xf, b0[m]);
#pragma unroll
        for (int m = 0; m < 8; ++m) g[m] = MFMA(A0h[m], h1f, g[m]);
        float hn1[4];
#pragma unroll
        for (int r = 0; r < 4; ++r) {   // own half only: gates m = 2*gate + mh
            float ei = __expf(-g[0 + mh][r]);
            float ef = __expf(-g[2 + mh][r]);
            float eg = __expf(-2.0f * g[4 + mh][r]);
            float eo = __expf(-g[6 + mh][r]);
            float ig = (1.0f - eg) * __builtin_amdgcn_rcpf(fmaf(ei, eg, ei) + eg + 1.0f);
            float fv = __builtin_amdgcn_rcpf(1.0f + ef);
            float c  = fmaf(fv, c1[r], ig);
            c1[r] = c;
            float ec = __expf(-2.0f * c);
            hn1[r] = (1.0f - ec) * __builtin_amdgcn_rcpf(fmaf(eo, ec, eo) + ec + 1.0f);
        }
        h1f = join_bfrag(hn1, mh1);

        // ---------- layer 1 ----------
#pragma unroll
        for (int m = 0; m < 8; ++m) g[m] = MFMA(A1i[m], h1f, b1[m]);
#pragma unroll
        for (int m = 0; m < 8; ++m) g[m] = MFMA(A1h[m], h2f, g[m]);
        float hn2[4];
#pragma unroll
        for (int r = 0; r < 4; ++r) {
            float ei = __expf(-g[0 + mh][r]);
            float ef = __expf(-g[2 + mh][r]);
            float eg = __expf(-2.0f * g[4 + mh][r]);
            float eo = __expf(-g[6 + mh][r]);
            float ig = (1.0f - eg) * __builtin_amdgcn_rcpf(fmaf(ei, eg, ei) + eg + 1.0f);
            float fv = __builtin_amdgcn_rcpf(1.0f + ef);
            float c  = fmaf(fv, c2[r], ig);
            c2[r] = c;
            float ec = __expf(-2.0f * c);
            float h  = (1.0f - ec) * __builtin_amdgcn_rcpf(fmaf(eo, ec, eo) + ec + 1.0f);
            hn2[r] = h;
            hsum[r] += h;
        }
        h2f = join_bfrag(hn2, mh1);
    }

    // ---------- fc head ----------
    float hs[4];
#pragma unroll
    for (int r = 0; r < 4; ++r) hs[r] = hsum[r] * (1.0f / NT);
    bf16x8 hsf = join_bfrag(hs, mh1);

    int gw[4];
    {
        const float* gp = Gu + (size_t)batch * NG;
#pragma unroll
        for (int q = 0; q < 4; ++q) {
            int k = k0 + 2 * q;
            float lo = (k     < NG) ? gp[k]     : 0.0f;
            float hi = (k + 1 < NG) ? gp[k + 1] : 0.0f;
            gw[q] = pack2(lo, hi);
        }
    }
    i32x4 gv_ = { gw[0], gw[1], gw[2], gw[3] };
    bf16x8 guf = __builtin_bit_cast(bf16x8, gv_);

    f32x4 zero4 = { 0.0f, 0.0f, 0.0f, 0.0f };
    f32x4 L[2];
#pragma unroll
    for (int m2 = 0; m2 < 2; ++m2) L[m2] = MFMA(Afc0[m2], hsf, zero4);
#pragma unroll
    for (int m2 = 0; m2 < 2; ++m2) L[m2] = MFMA(Afc1[m2], guf, L[m2]);

    if (bl < 8) {   // col-copies hold identical logits; one writer per batch
#pragma unroll
        for (int m2 = 0; m2 < 2; ++m2)
#pragma unroll
            for (int r = 0; r < 4; ++r) {
                int row = 16 * m2 + 4 * g4 + r;
                if (row < NG) {
                    float v = L[m2][r] + bfc[row];
                    out[(size_t)batch * NG + row] = v;
                    out[(size_t)NB * NG + (size_t)batch * NG + row] =
                        __builtin_amdgcn_rcpf(1.0f + __expf(-v));
                }
            }
    }
}

extern "C" void kernel_launch(void* const* d_in, const int* in_sizes, int n_in,
                              void* d_out, int out_size, void* d_ws, size_t ws_size,
                              hipStream_t stream) {
    const float* X    = (const float*)d_in[0];
    const float* Gu   = (const float*)d_in[1];
    const float* H0   = (const float*)d_in[2];
    const float* C0   = (const float*)d_in[3];
    const float* Wih0 = (const float*)d_in[4];
    const float* Whh0 = (const float*)d_in[5];
    const float* bih0 = (const float*)d_in[6];
    const float* bhh0 = (const float*)d_in[7];
    const float* Wih1 = (const float*)d_in[8];
    const float* Whh1 = (const float*)d_in[9];
    const float* bih1 = (const float*)d_in[10];
    const float* bhh1 = (const float*)d_in[11];
    const float* Wfc  = (const float*)d_in[12];
    const float* bfc  = (const float*)d_in[13];
    float* out = (float*)d_out;

    dim3 grid(NB / 8 / 4), block(256);  // 512 blocks x 4 waves = 2048 waves -> 2/SIMD
    hipLaunchKernelGGL(lstm_dup2, grid, block, 0, stream,
                       X, Gu, H0, C0, Wih0, Whh0, bih0, bhh0,
                       Wih1, Whh1, bih1, bhh1, Wfc, bfc, out);
}

// Round 12
// 112.991 us; speedup vs baseline: 6.9003x; 6.9003x over previous
//
#include <hip/hip_runtime.h>
#include <hip/hip_bf16.h>

#define NB 16384
#define NT 32
#define NI 27
#define NH 32
#define NG 26

typedef __attribute__((ext_vector_type(8))) short bf16x8;
typedef __attribute__((ext_vector_type(4))) float f32x4;
typedef __attribute__((ext_vector_type(4))) int   i32x4;

#define MFMA(a, b, c) __builtin_amdgcn_mfma_f32_16x16x32_bf16((a), (b), (c), 0, 0, 0)
#define SWZ_XOR8 0x201F   // BitMode: xor=8, and=0x1F, or=0 -> lane <-> lane^8

static __device__ __forceinline__ int pack2(float lo, float hi) {
    unsigned short a = __builtin_bit_cast(unsigned short, __float2bfloat16(lo));
    unsigned short b = __builtin_bit_cast(unsigned short, __float2bfloat16(hi));
    return (int)(((unsigned)b << 16) | (unsigned)a);
}

// MFMA A-fragment loader. perm=false: lane supplies cols kbase+8*g4+2q(+1).
// perm=true: columns permuted by pi(8*g4+j) = 16*(j>>2) + 4*g4 + (j&3) so the
// B-operand packs directly from act-layout registers (verified R9-R11).
static __device__ __forceinline__ bf16x8 load_wfrag(const float* __restrict__ W,
                                                    int rowlen, int nrows, int row,
                                                    int g4, int kbase, bool perm) {
    int w[4];
#pragma unroll
    for (int q = 0; q < 4; ++q) {
        int klo = perm ? (16 * (q >> 1) + 4 * g4 + ((2 * q) & 3))
                       : (kbase + 8 * g4 + 2 * q);
        int khi = klo + 1;
        float lo = (row < nrows && klo < rowlen) ? W[row * rowlen + klo] : 0.0f;
        float hi = (row < nrows && khi < rowlen) ? W[row * rowlen + khi] : 0.0f;
        w[q] = pack2(lo, hi);
    }
    i32x4 v = { w[0], w[1], w[2], w[3] };
    return __builtin_bit_cast(bf16x8, v);
}

// Wih0 loader with the bias folded into virtual column NI (x[NI] := 1.0):
// col k<NI -> weight; k==NI -> bih0+bhh0; k>NI -> 0. Frees the b0[] C-init regs.
static __device__ __forceinline__ bf16x8 load_wfrag_xb(const float* __restrict__ W,
                                                       const float* __restrict__ bi,
                                                       const float* __restrict__ bh,
                                                       int row, int g4) {
    int w[4];
#pragma unroll
    for (int q = 0; q < 4; ++q) {
        int klo = 8 * g4 + 2 * q;
        int khi = klo + 1;
        float lo = (klo < NI) ? W[row * NI + klo] : ((klo == NI) ? bi[row] + bh[row] : 0.0f);
        float hi = (khi < NI) ? W[row * NI + khi] : ((khi == NI) ? bi[row] + bh[row] : 0.0f);
        w[q] = pack2(lo, hi);
    }
    i32x4 v = { w[0], w[1], w[2], w[3] };
    return __builtin_bit_cast(bf16x8, v);
}

// Own-half act values (hn[r] = h[16*mh_own + 4*g4 + r]) -> full pi-order B-frag
// via one conflict-free ds_swizzle pair with the partner col-copy lane (lane^8).
// Verified (R10/R11 absmax matched R9).
static __device__ __forceinline__ bf16x8 join_bfrag(const float hn[4], bool mh1) {
    int p0 = pack2(hn[0], hn[1]);
    int p1 = pack2(hn[2], hn[3]);
    int q0 = __builtin_amdgcn_ds_swizzle(p0, SWZ_XOR8);
    int q1 = __builtin_amdgcn_ds_swizzle(p1, SWZ_XOR8);
    i32x4 v = { mh1 ? q0 : p0, mh1 ? q1 : p1, mh1 ? p0 : q0, mh1 ? p1 : q1 };
    return __builtin_bit_cast(bf16x8, v);
}

// 8 batches/wave duplicated into cols bl and bl+8; act split by col-copy (4
// hidden units/lane). All register-array indices are compile-time (rule #20:
// R10/R11's g[0+mh] runtime indexing demoted g[] to scratch -> 10x issue count
// + occupancy cap; fixed here with explicit cndmask selects).
__global__ __launch_bounds__(256)
void lstm_dup3(const float* __restrict__ X,   // [B,T,I] flat, consumed as [T,B,I]
               const float* __restrict__ Gu,  // [B,26]
               const float* __restrict__ H0, const float* __restrict__ C0,
               const float* __restrict__ Wih0, const float* __restrict__ Whh0,
               const float* __restrict__ bih0, const float* __restrict__ bhh0,
               const float* __restrict__ Wih1, const float* __restrict__ Whh1,
               const float* __restrict__ bih1, const float* __restrict__ bhh1,
               const float* __restrict__ Wfc, const float* __restrict__ bfc,
               float* __restrict__ out)
{
    const int lane = threadIdx.x & 63;
    const int bl   = lane & 15;          // col (two cols per batch)
    const int g4   = lane >> 4;
    const int k0   = 8 * g4;
    const int wid  = blockIdx.x * (blockDim.x >> 6) + (threadIdx.x >> 6);
    const int batch = wid * 8 + (bl & 7);
    const bool mh1 = (bl >> 3) != 0;     // owned hidden half: [16,32) if true

    // ---------- persistent weights (h-consumers pi-permuted; layer-0 bias in-weight) ----------
    bf16x8 A0x[8], A0h[8], A1i[8], A1h[8];
    f32x4  b1[8];
#pragma unroll
    for (int m = 0; m < 8; ++m) {
        A0x[m] = load_wfrag_xb(Wih0, bih0, bhh0, 16 * m + bl, g4);
        A0h[m] = load_wfrag(Whh0, NH, 4 * NH, 16 * m + bl, g4, 0, true);
        A1i[m] = load_wfrag(Wih1, NH, 4 * NH, 16 * m + bl, g4, 0, true);
        A1h[m] = load_wfrag(Whh1, NH, 4 * NH, 16 * m + bl, g4, 0, true);
#pragma unroll
        for (int r = 0; r < 4; ++r) {
            int gr = 16 * m + 4 * g4 + r;
            b1[m][r] = bih1[gr] + bhh1[gr];
        }
    }
    bf16x8 Afc0[2], Afc1[2];
#pragma unroll
    for (int m2 = 0; m2 < 2; ++m2) {
        Afc0[m2] = load_wfrag(Wfc, NH + NG, NG, 16 * m2 + bl, g4, 0, true);
        Afc1[m2] = load_wfrag(Wfc, NH + NG, NG, 16 * m2 + bl, g4, NH, false);
    }

    // ---------- state init (init aliases h0/c0; both col-copies identical) ----------
    const float* h0p = H0 + (size_t)batch * NH;
    const float* c0p = C0 + (size_t)batch * NH;
    i32x4 hv = { pack2(h0p[4 * g4],          h0p[4 * g4 + 1]),
                 pack2(h0p[4 * g4 + 2],      h0p[4 * g4 + 3]),
                 pack2(h0p[16 + 4 * g4],     h0p[16 + 4 * g4 + 1]),
                 pack2(h0p[16 + 4 * g4 + 2], h0p[16 + 4 * g4 + 3]) };
    bf16x8 h1f = __builtin_bit_cast(bf16x8, hv);
    bf16x8 h2f = h1f;
    float c1[4], c2[4], hsum[4];
#pragma unroll
    for (int r = 0; r < 4; ++r) {
        float c = c0p[(mh1 ? 16 : 0) + 4 * g4 + r];   // own units only
        c1[r] = c; c2[r] = c; hsum[r] = 0.0f;
    }

    // x prefetch (t=0); virtual col NI carries 1.0 for the folded bias
    float xn[8];
    {
        const float* xp = X + (size_t)batch * NI;
#pragma unroll
        for (int j = 0; j < 8; ++j) {
            int k = k0 + j;
            xn[j] = (k < NI) ? xp[k] : ((k == NI) ? 1.0f : 0.0f);
        }
    }

    const f32x4 zero4 = { 0.0f, 0.0f, 0.0f, 0.0f };

#pragma unroll 1
    for (int t = 0; t < NT; ++t) {
        int xw[4];
#pragma unroll
        for (int q = 0; q < 4; ++q) xw[q] = pack2(xn[2 * q], xn[2 * q + 1]);
        i32x4 xv = { xw[0], xw[1], xw[2], xw[3] };
        bf16x8 xf = __builtin_bit_cast(bf16x8, xv);
        if (t + 1 < NT) {
            const float* xp = X + ((size_t)(t + 1) * NB + batch) * NI;
#pragma unroll
            for (int j = 0; j < 8; ++j) {
                int k = k0 + j;
                xn[j] = (k < NI) ? xp[k] : ((k == NI) ? 1.0f : 0.0f);
            }
        }

        f32x4 g[8];
        // ---------- layer 0 (bias comes via x's 1.0 column) ----------
#pragma unroll
        for (int m = 0; m < 8; ++m) g[m] = MFMA(A0x[m], xf, zero4);
#pragma unroll
        for (int m = 0; m < 8; ++m) g[m] = MFMA(A0h[m], h1f, g[m]);
        float hn1[4];
#pragma unroll
        for (int r = 0; r < 4; ++r) {   // compile-time indices + cndmask selects
            float gi_ = mh1 ? g[1][r] : g[0][r];
            float gf_ = mh1 ? g[3][r] : g[2][r];
            float gg_ = mh1 ? g[5][r] : g[4][r];
            float go_ = mh1 ? g[7][r] : g[6][r];
            float ei = __expf(-gi_);
            float ef = __expf(-gf_);
            float eg = __expf(-2.0f * gg_);
            float eo = __expf(-go_);
            float ig = (1.0f - eg) * __builtin_amdgcn_rcpf(fmaf(ei, eg, ei) + eg + 1.0f);
            float fv = __builtin_amdgcn_rcpf(1.0f + ef);
            float c  = fmaf(fv, c1[r], ig);
            c1[r] = c;
            float ec = __expf(-2.0f * c);
            hn1[r] = (1.0f - ec) * __builtin_amdgcn_rcpf(fmaf(eo, ec, eo) + ec + 1.0f);
        }
        h1f = join_bfrag(hn1, mh1);

        // ---------- layer 1 ----------
#pragma unroll
        for (int m = 0; m < 8; ++m) g[m] = MFMA(A1i[m], h1f, b1[m]);
#pragma unroll
        for (int m = 0; m < 8; ++m) g[m] = MFMA(A1h[m], h2f, g[m]);
        float hn2[4];
#pragma unroll
        for (int r = 0; r < 4; ++r) {
            float gi_ = mh1 ? g[1][r] : g[0][r];
            float gf_ = mh1 ? g[3][r] : g[2][r];
            float gg_ = mh1 ? g[5][r] : g[4][r];
            float go_ = mh1 ? g[7][r] : g[6][r];
            float ei = __expf(-gi_);
            float ef = __expf(-gf_);
            float eg = __expf(-2.0f * gg_);
            float eo = __expf(-go_);
            float ig = (1.0f - eg) * __builtin_amdgcn_rcpf(fmaf(ei, eg, ei) + eg + 1.0f);
            float fv = __builtin_amdgcn_rcpf(1.0f + ef);
            float c  = fmaf(fv, c2[r], ig);
            c2[r] = c;
            float ec = __expf(-2.0f * c);
            float h  = (1.0f - ec) * __builtin_amdgcn_rcpf(fmaf(eo, ec, eo) + ec + 1.0f);
            hn2[r] = h;
            hsum[r] += h;
        }
        h2f = join_bfrag(hn2, mh1);
    }

    // ---------- fc head ----------
    float hs[4];
#pragma unroll
    for (int r = 0; r < 4; ++r) hs[r] = hsum[r] * (1.0f / NT);
    bf16x8 hsf = join_bfrag(hs, mh1);

    int gw[4];
    {
        const float* gp = Gu + (size_t)batch * NG;
#pragma unroll
        for (int q = 0; q < 4; ++q) {
            int k = k0 + 2 * q;
            float lo = (k     < NG) ? gp[k]     : 0.0f;
            float hi = (k + 1 < NG) ? gp[k + 1] : 0.0f;
            gw[q] = pack2(lo, hi);
        }
    }
    i32x4 gv_ = { gw[0], gw[1], gw[2], gw[3] };
    bf16x8 guf = __builtin_bit_cast(bf16x8, gv_);

    f32x4 L[2];
#pragma unroll
    for (int m2 = 0; m2 < 2; ++m2) L[m2] = MFMA(Afc0[m2], hsf, zero4);
#pragma unroll
    for (int m2 = 0; m2 < 2; ++m2) L[m2] = MFMA(Afc1[m2], guf, L[m2]);

    if (bl < 8) {   // col-copies hold identical logits; one writer per batch
#pragma unroll
        for (int m2 = 0; m2 < 2; ++m2)
#pragma unroll
            for (int r = 0; r < 4; ++r) {
                int row = 16 * m2 + 4 * g4 + r;
                if (row < NG) {
                    float v = L[m2][r] + bfc[row];
                    out[(size_t)batch * NG + row] = v;
                    out[(size_t)NB * NG + (size_t)batch * NG + row] =
                        __builtin_amdgcn_rcpf(1.0f + __expf(-v));
                }
            }
    }
}

extern "C" void kernel_launch(void* const* d_in, const int* in_sizes, int n_in,
                              void* d_out, int out_size, void* d_ws, size_t ws_size,
                              hipStream_t stream) {
    const float* X    = (const float*)d_in[0];
    const float* Gu   = (const float*)d_in[1];
    const float* H0   = (const float*)d_in[2];
    const float* C0   = (const float*)d_in[3];
    const float* Wih0 = (const float*)d_in[4];
    const float* Whh0 = (const float*)d_in[5];
    const float* bih0 = (const float*)d_in[6];
    const float* bhh0 = (const float*)d_in[7];
    const float* Wih1 = (const float*)d_in[8];
    const float* Whh1 = (const float*)d_in[9];
    const float* bih1 = (const float*)d_in[10];
    const float* bhh1 = (const float*)d_in[11];
    const float* Wfc  = (const float*)d_in[12];
    const float* bfc  = (const float*)d_in[13];
    float* out = (float*)d_out;

    dim3 grid(NB / 8 / 4), block(256);  // 512 blocks x 4 waves = 2048 waves -> 2/SIMD
    hipLaunchKernelGGL(lstm_dup3, grid, block, 0, stream,
                       X, Gu, H0, C0, Wih0, Whh0, bih0, bhh0,
                       Wih1, Whh1, bih1, bhh1, Wfc, bfc, out);
}

// Round 13
// 67.946 us; speedup vs baseline: 11.4747x; 1.6629x over previous
//
#include <hip/hip_runtime.h>
#include <hip/hip_bf16.h>

#define NB 16384
#define NT 32
#define NI 27
#define NH 32
#define NG 26

typedef __attribute__((ext_vector_type(8))) short bf16x8;
typedef __attribute__((ext_vector_type(4))) float f32x4;
typedef __attribute__((ext_vector_type(4))) int   i32x4;

#define MFMA(a, b, c) __builtin_amdgcn_mfma_f32_16x16x32_bf16((a), (b), (c), 0, 0, 0)
#define SWZ_XOR8 0x201F   // BitMode: xor=8, and=0x1F -> lane <-> lane^8

static __device__ __forceinline__ int pack2(float lo, float hi) {
    unsigned short a = __builtin_bit_cast(unsigned short, __float2bfloat16(lo));
    unsigned short b = __builtin_bit_cast(unsigned short, __float2bfloat16(hi));
    return (int)(((unsigned)b << 16) | (unsigned)a);
}

// A-fragment builders (verified R9-R12). perm: pi(8*g4+j)=16*(j>>2)+4*g4+(j&3).
static __device__ __forceinline__ i32x4 make_wfrag(const float* __restrict__ W,
                                                   int rowlen, int nrows, int row,
                                                   int g4, int kbase, bool perm) {
    int w[4];
#pragma unroll
    for (int q = 0; q < 4; ++q) {
        int klo = perm ? (16 * (q >> 1) + 4 * g4 + ((2 * q) & 3))
                       : (kbase + 8 * g4 + 2 * q);
        int khi = klo + 1;
        float lo = (row < nrows && klo < rowlen) ? W[row * rowlen + klo] : 0.0f;
        float hi = (row < nrows && khi < rowlen) ? W[row * rowlen + khi] : 0.0f;
        w[q] = pack2(lo, hi);
    }
    i32x4 v = { w[0], w[1], w[2], w[3] };
    return v;
}

// Wih0 with layer-0 bias folded into virtual column NI (x[NI] := 1.0).
static __device__ __forceinline__ i32x4 make_wfrag_xb(const float* __restrict__ W,
                                                      const float* __restrict__ bi,
                                                      const float* __restrict__ bh,
                                                      int row, int g4) {
    int w[4];
#pragma unroll
    for (int q = 0; q < 4; ++q) {
        int klo = 8 * g4 + 2 * q;
        int khi = klo + 1;
        float lo = (klo < NI) ? W[row * NI + klo] : ((klo == NI) ? bi[row] + bh[row] : 0.0f);
        float hi = (khi < NI) ? W[row * NI + khi] : ((khi == NI) ? bi[row] + bh[row] : 0.0f);
        w[q] = pack2(lo, hi);
    }
    i32x4 v = { w[0], w[1], w[2], w[3] };
    return v;
}

// Own-half act (hn[r] = h[16*mh+4*g4+r]) -> full pi-order B-frag via partner
// lane (lane^8) ds_swizzle. Verified R10-R12.
static __device__ __forceinline__ bf16x8 join_bfrag(const float hn[4], bool mh1) {
    int p0 = pack2(hn[0], hn[1]);
    int p1 = pack2(hn[2], hn[3]);
    int q0 = __builtin_amdgcn_ds_swizzle(p0, SWZ_XOR8);
    int q1 = __builtin_amdgcn_ds_swizzle(p1, SWZ_XOR8);
    i32x4 v = { mh1 ? q0 : p0, mh1 ? q1 : p1, mh1 ? p0 : q0, mh1 ? p1 : q1 };
    return __builtin_bit_cast(bf16x8, v);
}

// Weights live in LDS as pre-packed fragments (staged once, read per step via
// ds_read_b128) so per-wave VGPR <= 128 -> 2 independent waves/SIMD with NO
// barriers in the recurrence (R8/R5's barrier-coupled pairs phase-alternated).
// Wave = R12's dup structure: 8 batches in 2 col-copies, act halved per lane.
__global__ __launch_bounds__(256, 2)
void lstm_lds(const float* __restrict__ X,   // [B,T,I] flat, consumed as [T,B,I]
              const float* __restrict__ Gu,  // [B,26]
              const float* __restrict__ H0, const float* __restrict__ C0,
              const float* __restrict__ Wih0, const float* __restrict__ Whh0,
              const float* __restrict__ bih0, const float* __restrict__ bhh0,
              const float* __restrict__ Wih1, const float* __restrict__ Whh1,
              const float* __restrict__ bih1, const float* __restrict__ bhh1,
              const float* __restrict__ Wfc, const float* __restrict__ bfc,
              float* __restrict__ out)
{
    __shared__ i32x4 sA0x[512], sA0h[512], sA1i[512], sA1h[512];  // [m][lane]
    __shared__ f32x4 sB1[32];    // [m][g4] layer-1 bias C-init
    __shared__ i32x4 sAfc[256];  // [part][m2][lane]

    const int tid  = threadIdx.x;
    const int lane = tid & 63;
    const int bl   = lane & 15;
    const int g4   = lane >> 4;
    const int k0   = 8 * g4;
    const int wid  = blockIdx.x * 4 + (tid >> 6);
    const int batch = wid * 8 + (bl & 7);
    const bool mh1 = (bl >> 3) != 0;

    // ---------- one-time cooperative staging ----------
#pragma unroll 1
    for (int slot = tid; slot < 512; slot += 256) {
        int m = slot >> 6, ln = slot & 63;
        int bs = ln & 15, gs = ln >> 4;
        sA0x[slot] = make_wfrag_xb(Wih0, bih0, bhh0, 16 * m + bs, gs);
        sA0h[slot] = make_wfrag(Whh0, NH, 4 * NH, 16 * m + bs, gs, 0, true);
        sA1i[slot] = make_wfrag(Wih1, NH, 4 * NH, 16 * m + bs, gs, 0, true);
        sA1h[slot] = make_wfrag(Whh1, NH, 4 * NH, 16 * m + bs, gs, 0, true);
    }
    if (tid < 32) {
        int m = tid >> 2, q4 = tid & 3;
        f32x4 b;
#pragma unroll
        for (int r = 0; r < 4; ++r) {
            int gr = 16 * m + 4 * q4 + r;
            b[r] = bih1[gr] + bhh1[gr];
        }
        sB1[tid] = b;
    }
    {
        int part = tid >> 7, m2 = (tid >> 6) & 1, ln = tid & 63;
        int bs = ln & 15, gs = ln >> 4;
        sAfc[tid] = part ? make_wfrag(Wfc, NH + NG, NG, 16 * m2 + bs, gs, NH, false)
                         : make_wfrag(Wfc, NH + NG, NG, 16 * m2 + bs, gs, 0, true);
    }
    __syncthreads();   // only barrier; recurrence below is barrier-free

    // ---------- state init (init aliases h0/c0; both col-copies identical) ----------
    const float* h0p = H0 + (size_t)batch * NH;
    const float* c0p = C0 + (size_t)batch * NH;
    i32x4 hv = { pack2(h0p[4 * g4],          h0p[4 * g4 + 1]),
                 pack2(h0p[4 * g4 + 2],      h0p[4 * g4 + 3]),
                 pack2(h0p[16 + 4 * g4],     h0p[16 + 4 * g4 + 1]),
                 pack2(h0p[16 + 4 * g4 + 2], h0p[16 + 4 * g4 + 3]) };
    bf16x8 h1f = __builtin_bit_cast(bf16x8, hv);
    bf16x8 h2f = h1f;
    float c1[4], c2[4], hsum[4];
#pragma unroll
    for (int r = 0; r < 4; ++r) {
        float c = c0p[(mh1 ? 16 : 0) + 4 * g4 + r];
        c1[r] = c; c2[r] = c; hsum[r] = 0.0f;
    }

    // x prefetch (t=0); virtual col NI carries 1.0 for the folded layer-0 bias
    float xn[8];
    {
        const float* xp = X + (size_t)batch * NI;
#pragma unroll
        for (int j = 0; j < 8; ++j) {
            int k = k0 + j;
            xn[j] = (k < NI) ? xp[k] : ((k == NI) ? 1.0f : 0.0f);
        }
    }

    const f32x4 zero4 = { 0.0f, 0.0f, 0.0f, 0.0f };

#pragma unroll 1
    for (int t = 0; t < NT; ++t) {
        int xw[4];
#pragma unroll
        for (int q = 0; q < 4; ++q) xw[q] = pack2(xn[2 * q], xn[2 * q + 1]);
        i32x4 xv = { xw[0], xw[1], xw[2], xw[3] };
        bf16x8 xf = __builtin_bit_cast(bf16x8, xv);
        if (t + 1 < NT) {
            const float* xp = X + ((size_t)(t + 1) * NB + batch) * NI;
#pragma unroll
            for (int j = 0; j < 8; ++j) {
                int k = k0 + j;
                xn[j] = (k < NI) ? xp[k] : ((k == NI) ? 1.0f : 0.0f);
            }
        }

        f32x4 g[8];
        // ---------- layer 0 (weights streamed from LDS) ----------
#pragma unroll
        for (int m = 0; m < 8; ++m)
            g[m] = MFMA(__builtin_bit_cast(bf16x8, sA0x[m * 64 + lane]), xf, zero4);
#pragma unroll
        for (int m = 0; m < 8; ++m)
            g[m] = MFMA(__builtin_bit_cast(bf16x8, sA0h[m * 64 + lane]), h1f, g[m]);
        float hn1[4];
#pragma unroll
        for (int r = 0; r < 4; ++r) {   // compile-time indices + cndmask selects (rule #20)
            float gi_ = mh1 ? g[1][r] : g[0][r];
            float gf_ = mh1 ? g[3][r] : g[2][r];
            float gg_ = mh1 ? g[5][r] : g[4][r];
            float go_ = mh1 ? g[7][r] : g[6][r];
            float ei = __expf(-gi_);
            float ef = __expf(-gf_);
            float eg = __expf(-2.0f * gg_);
            float eo = __expf(-go_);
            float ig = (1.0f - eg) * __builtin_amdgcn_rcpf(fmaf(ei, eg, ei) + eg + 1.0f);
            float fv = __builtin_amdgcn_rcpf(1.0f + ef);
            float c  = fmaf(fv, c1[r], ig);
            c1[r] = c;
            float ec = __expf(-2.0f * c);
            hn1[r] = (1.0f - ec) * __builtin_amdgcn_rcpf(fmaf(eo, ec, eo) + ec + 1.0f);
        }
        h1f = join_bfrag(hn1, mh1);

        // ---------- layer 1 ----------
#pragma unroll
        for (int m = 0; m < 8; ++m)
            g[m] = MFMA(__builtin_bit_cast(bf16x8, sA1i[m * 64 + lane]), h1f, sB1[m * 4 + g4]);
#pragma unroll
        for (int m = 0; m < 8; ++m)
            g[m] = MFMA(__builtin_bit_cast(bf16x8, sA1h[m * 64 + lane]), h2f, g[m]);
        float hn2[4];
#pragma unroll
        for (int r = 0; r < 4; ++r) {
            float gi_ = mh1 ? g[1][r] : g[0][r];
            float gf_ = mh1 ? g[3][r] : g[2][r];
            float gg_ = mh1 ? g[5][r] : g[4][r];
            float go_ = mh1 ? g[7][r] : g[6][r];
            float ei = __expf(-gi_);
            float ef = __expf(-gf_);
            float eg = __expf(-2.0f * gg_);
            float eo = __expf(-go_);
            float ig = (1.0f - eg) * __builtin_amdgcn_rcpf(fmaf(ei, eg, ei) + eg + 1.0f);
            float fv = __builtin_amdgcn_rcpf(1.0f + ef);
            float c  = fmaf(fv, c2[r], ig);
            c2[r] = c;
            float ec = __expf(-2.0f * c);
            float h  = (1.0f - ec) * __builtin_amdgcn_rcpf(fmaf(eo, ec, eo) + ec + 1.0f);
            hn2[r] = h;
            hsum[r] += h;
        }
        h2f = join_bfrag(hn2, mh1);
    }

    // ---------- fc head ----------
    float hs[4];
#pragma unroll
    for (int r = 0; r < 4; ++r) hs[r] = hsum[r] * (1.0f / NT);
    bf16x8 hsf = join_bfrag(hs, mh1);

    int gw[4];
    {
        const float* gp = Gu + (size_t)batch * NG;
#pragma unroll
        for (int q = 0; q < 4; ++q) {
            int k = k0 + 2 * q;
            float lo = (k     < NG) ? gp[k]     : 0.0f;
            float hi = (k + 1 < NG) ? gp[k + 1] : 0.0f;
            gw[q] = pack2(lo, hi);
        }
    }
    i32x4 gv_ = { gw[0], gw[1], gw[2], gw[3] };
    bf16x8 guf = __builtin_bit_cast(bf16x8, gv_);

    f32x4 L[2];
#pragma unroll
    for (int m2 = 0; m2 < 2; ++m2)
        L[m2] = MFMA(__builtin_bit_cast(bf16x8, sAfc[m2 * 64 + lane]), hsf, zero4);
#pragma unroll
    for (int m2 = 0; m2 < 2; ++m2)
        L[m2] = MFMA(__builtin_bit_cast(bf16x8, sAfc[128 + m2 * 64 + lane]), guf, L[m2]);

    if (bl < 8) {   // col-copies hold identical logits; one writer per batch
#pragma unroll
        for (int m2 = 0; m2 < 2; ++m2)
#pragma unroll
            for (int r = 0; r < 4; ++r) {
                int row = 16 * m2 + 4 * g4 + r;
                if (row < NG) {
                    float v = L[m2][r] + bfc[row];
                    out[(size_t)batch * NG + row] = v;
                    out[(size_t)NB * NG + (size_t)batch * NG + row] =
                        __builtin_amdgcn_rcpf(1.0f + __expf(-v));
                }
            }
    }
}

extern "C" void kernel_launch(void* const* d_in, const int* in_sizes, int n_in,
                              void* d_out, int out_size, void* d_ws, size_t ws_size,
                              hipStream_t stream) {
    const float* X    = (const float*)d_in[0];
    const float* Gu   = (const float*)d_in[1];
    const float* H0   = (const float*)d_in[2];
    const float* C0   = (const float*)d_in[3];
    const float* Wih0 = (const float*)d_in[4];
    const float* Whh0 = (const float*)d_in[5];
    const float* bih0 = (const float*)d_in[6];
    const float* bhh0 = (const float*)d_in[7];
    const float* Wih1 = (const float*)d_in[8];
    const float* Whh1 = (const float*)d_in[9];
    const float* bih1 = (const float*)d_in[10];
    const float* bhh1 = (const float*)d_in[11];
    const float* Wfc  = (const float*)d_in[12];
    const float* bfc  = (const float*)d_in[13];
    float* out = (float*)d_out;

    dim3 grid(NB / 8 / 4), block(256);  // 512 blocks x 4 waves = 2048 waves -> 2/SIMD
    hipLaunchKernelGGL(lstm_lds, grid, block, 0, stream,
                       X, Gu, H0, C0, Wih0, Whh0, bih0, bhh0,
                       Wih1, Whh1, bih1, bhh1, Wfc, bfc, out);
}